// Round 1
// baseline (510.723 us; speedup 1.0000x reference)
//
#include <hip/hip_runtime.h>
#include <hip/hip_bf16.h>

// Problem: B=16, S=1024, D=1024, H=8, dh=128. M = B*S = 16384.
#define B_ 16
#define S_ 1024
#define D_ 1024
#define H_ 8

typedef __attribute__((ext_vector_type(4))) float f32x4;
typedef __attribute__((ext_vector_type(8))) short s16x8;
typedef __attribute__((ext_vector_type(4))) short s16x4;
typedef unsigned int u32;

static __device__ __forceinline__ short f2bf(float x) {
  union { __hip_bfloat16 h; short s; } cv;
  cv.h = __float2bfloat16(x);
  return cv.s;
}
static __device__ __forceinline__ float bf2f(short x) {
  union { float f; u32 u; } cv;
  cv.u = ((u32)(unsigned short)x) << 16;
  return cv.f;
}
static __device__ __forceinline__ void async16(const void* g, void* l) {
  __builtin_amdgcn_global_load_lds((const __attribute__((address_space(1))) u32*)g,
                                   (__attribute__((address_space(3))) u32*)l, 16, 0, 0);
}

// ---------------- f32 -> bf16 convert, 8 elems/thread ----------------
__global__ __launch_bounds__(256) void cvt_bf16(const float* __restrict__ s,
                                                short* __restrict__ d, int n8) {
  int i = blockIdx.x * 256 + threadIdx.x;
  if (i >= n8) return;
  const float4* s4 = (const float4*)s;
  float4 a = s4[2 * i], b = s4[2 * i + 1];
  s16x8 r;
  r[0] = f2bf(a.x); r[1] = f2bf(a.y); r[2] = f2bf(a.z); r[3] = f2bf(a.w);
  r[4] = f2bf(b.x); r[5] = f2bf(b.y); r[6] = f2bf(b.z); r[7] = f2bf(b.w);
  *(s16x8*)(d + (size_t)i * 8) = r;
}

// ---------------- QKV projection GEMM: C = relu(A[M,K] @ W[N,K]^T + bias) ---
// 128x128 tile, BK=64, 4 waves (2x2), 16x16x32 bf16 MFMA.
// LDS rows are 128B; XOR-swizzle byte ^= ((row&7)<<4) applied via pre-swizzled
// global source (linear global_load_lds dest) + swizzled ds_read (rule 21).
__global__ __launch_bounds__(256, 2) void gemm_qkv(
    const short* __restrict__ qb, const short* __restrict__ kb,
    const short* __restrict__ wq, const short* __restrict__ wk,
    const short* __restrict__ wv, const float* __restrict__ bq,
    const float* __restrict__ bk, const float* __restrict__ bv,
    short* __restrict__ Qb, short* __restrict__ Kb, short* __restrict__ Vb) {
  __shared__ short lA[128 * 64];
  __shared__ short lB[128 * 64];
  const short* A; const short* W; const float* bias; short* C;
  switch (blockIdx.z) {
    case 0:  A = qb; W = wq; bias = bq; C = Qb; break;
    case 1:  A = kb; W = wk; bias = bk; C = Kb; break;
    default: A = kb; W = wv; bias = bv; C = Vb; break;
  }
  const int t = threadIdx.x;
  const int w = t >> 6, l = t & 63, lg = l >> 4, li = l & 15;
  const int wr = w >> 1, wc = w & 1;
  const int m0 = blockIdx.y << 7, n0 = blockIdx.x << 7;

  f32x4 acc[4][4];
#pragma unroll
  for (int m = 0; m < 4; ++m)
#pragma unroll
    for (int n = 0; n < 4; ++n) acc[m][n] = {0.f, 0.f, 0.f, 0.f};

  const char* Ab = (const char*)A + (size_t)m0 * 2048;
  const char* Wb = (const char*)W + (size_t)n0 * 2048;

#pragma unroll 1
  for (int k0 = 0; k0 < 1024; k0 += 64) {
    __syncthreads();
#pragma unroll
    for (int it = 0; it < 4; ++it) {
      int e = it * 256 + t;                        // 0..1023, one 16B chunk each
      int row = e >> 3;                            // 0..127
      int sb = ((e & 7) << 4) ^ ((row & 7) << 4);  // pre-swizzled source byte
      async16(Ab + (size_t)row * 2048 + k0 * 2 + sb, (char*)lA + e * 16);
      async16(Wb + (size_t)row * 2048 + k0 * 2 + sb, (char*)lB + e * 16);
    }
    __syncthreads();
#pragma unroll
    for (int kk = 0; kk < 2; ++kk) {
      s16x8 af[4], bfr[4];
#pragma unroll
      for (int m = 0; m < 4; ++m) {
        int row = wr * 64 + m * 16 + li;
        af[m] = *(const s16x8*)((char*)lA + row * 128 +
                                ((kk * 64 + (lg << 4)) ^ ((row & 7) << 4)));
      }
#pragma unroll
      for (int n = 0; n < 4; ++n) {
        int row = wc * 64 + n * 16 + li;
        bfr[n] = *(const s16x8*)((char*)lB + row * 128 +
                                 ((kk * 64 + (lg << 4)) ^ ((row & 7) << 4)));
      }
#pragma unroll
      for (int m = 0; m < 4; ++m)
#pragma unroll
        for (int n = 0; n < 4; ++n)
          acc[m][n] = __builtin_amdgcn_mfma_f32_16x16x32_bf16(af[m], bfr[n],
                                                              acc[m][n], 0, 0, 0);
    }
  }
  // epilogue: bias + relu, bf16 store. C/D layout: col=lane&15, row=(lane>>4)*4+r
#pragma unroll
  for (int n = 0; n < 4; ++n) {
    int col = n0 + wc * 64 + n * 16 + li;
    float bb = bias[col];
#pragma unroll
    for (int m = 0; m < 4; ++m) {
      int row0 = m0 + wr * 64 + m * 16 + (lg << 2);
#pragma unroll
      for (int r = 0; r < 4; ++r) {
        float v = acc[m][n][r] + bb;
        C[(size_t)(row0 + r) * 1024 + col] = f2bf(v > 0.f ? v : 0.f);
      }
    }
  }
}

// ---------------- Flash attention ----------------
// Grid (S/128, B*H). Block = 4 waves; wave owns 32 q-rows. K/V tiles of 64.
// Q frags read from global once. K_lds swizzled (pre-swz source + swz read).
// V staged transposed into lV[d][k] (stride 72 elems = 144B, swz ((d>>3)&7)<<4).
// P staged bf16 into lP (swz (row&7)<<4), wave-private slices.
__global__ __launch_bounds__(256, 2) void attn_kernel(
    const short* __restrict__ Qb, const short* __restrict__ Kb,
    const short* __restrict__ Vb, short* __restrict__ Ob) {
  __shared__ short lK[64 * 128];   // 16 KB
  __shared__ short lV[128 * 72];   // 18 KB
  __shared__ short lP[128 * 64];   // 16 KB

  const int t = threadIdx.x;
  const int w = t >> 6, l = t & 63, lg = l >> 4, li = l & 15;
  const int bh = blockIdx.y;
  const int b = bh >> 3, h = bh & 7;
  const int q0 = blockIdx.x << 7;
  const size_t hbase = (size_t)b * (S_ * D_) + h * 128;

  s16x8 qf[2][4];
#pragma unroll
  for (int m = 0; m < 2; ++m)
#pragma unroll
    for (int kk = 0; kk < 4; ++kk) {
      int row = q0 + (w << 5) + m * 16 + li;
      qf[m][kk] = *(const s16x8*)(Qb + hbase + (size_t)row * D_ + kk * 32 + (lg << 3));
    }

  f32x4 o[2][8];
#pragma unroll
  for (int m = 0; m < 2; ++m)
#pragma unroll
    for (int nd = 0; nd < 8; ++nd) o[m][nd] = {0.f, 0.f, 0.f, 0.f};
  float mrow[2][4], lrow[2][4];
#pragma unroll
  for (int m = 0; m < 2; ++m)
#pragma unroll
    for (int r = 0; r < 4; ++r) { mrow[m][r] = -1e30f; lrow[m][r] = 0.f; }

  const float scale = 0.08838834764831845f;  // 1/sqrt(128)

#pragma unroll 1
  for (int kt = 0; kt < 16; ++kt) {
    __syncthreads();
    // stage K tile (64 x 128 bf16), linear dest + pre-swizzled source
    const char* Kt = (const char*)(Kb + hbase) + (size_t)(kt * 64) * 2048;
#pragma unroll
    for (int it = 0; it < 4; ++it) {
      int e = it * 256 + t;
      int krow = e >> 4;
      int sb = ((e & 15) << 4) ^ ((krow & 7) << 4);
      async16(Kt + (size_t)krow * 2048 + sb, (char*)lK + e * 16);
    }
    // stage V transposed: coalesced 16B global read, swizzled u16 scatter
    const short* Vt = Vb + hbase + (size_t)(kt * 64) * D_;
#pragma unroll
    for (int it = 0; it < 4; ++it) {
      int e = it * 256 + t;
      int vrow = e >> 4;             // k index 0..63
      int d0 = (e & 15) << 3;        // d chunk base
      s16x8 vv = *(const s16x8*)(Vt + (size_t)vrow * D_ + d0);
      int kb2 = (vrow << 1) ^ ((e & 7) << 4);  // ((d>>3)&7)==e&7 for all j<8
      char* dst = (char*)lV + (size_t)d0 * 144 + kb2;
#pragma unroll
      for (int j = 0; j < 8; ++j) *(short*)(dst + j * 144) = vv[j];
    }
    __syncthreads();

    // QK^T: sc rows = q (32), cols = k (64)
    f32x4 sc[2][4];
#pragma unroll
    for (int m = 0; m < 2; ++m)
#pragma unroll
      for (int n = 0; n < 4; ++n) sc[m][n] = {0.f, 0.f, 0.f, 0.f};
#pragma unroll
    for (int kk = 0; kk < 4; ++kk)
#pragma unroll
      for (int n = 0; n < 4; ++n) {
        int krow = n * 16 + li;
        s16x8 kf = *(const s16x8*)((char*)lK + krow * 256 +
                                   ((kk * 64 + (lg << 4)) ^ ((krow & 7) << 4)));
        sc[0][n] = __builtin_amdgcn_mfma_f32_16x16x32_bf16(qf[0][kk], kf, sc[0][n], 0, 0, 0);
        sc[1][n] = __builtin_amdgcn_mfma_f32_16x16x32_bf16(qf[1][kk], kf, sc[1][n], 0, 0, 0);
      }

    // online softmax (row r of sub-block m lives in 16-lane group lg, reg r)
#pragma unroll
    for (int m = 0; m < 2; ++m)
#pragma unroll
      for (int r = 0; r < 4; ++r) {
        float v = fmaxf(fmaxf(sc[m][0][r], sc[m][1][r]), fmaxf(sc[m][2][r], sc[m][3][r]));
        v = fmaxf(v, __shfl_xor(v, 1));
        v = fmaxf(v, __shfl_xor(v, 2));
        v = fmaxf(v, __shfl_xor(v, 4));
        v = fmaxf(v, __shfl_xor(v, 8));
        float mnew = fmaxf(mrow[m][r], v);
        float f = __expf((mrow[m][r] - mnew) * scale);
        mrow[m][r] = mnew;
        float ps = 0.f;
#pragma unroll
        for (int n = 0; n < 4; ++n) {
          float p = __expf((sc[m][n][r] - mnew) * scale);
          sc[m][n][r] = p;
          ps += p;
        }
        ps += __shfl_xor(ps, 1);
        ps += __shfl_xor(ps, 2);
        ps += __shfl_xor(ps, 4);
        ps += __shfl_xor(ps, 8);
        lrow[m][r] = lrow[m][r] * f + ps;
#pragma unroll
        for (int nd = 0; nd < 8; ++nd) o[m][nd][r] *= f;
      }

    // write P (bf16) to wave-private lP slice, swizzled
#pragma unroll
    for (int m = 0; m < 2; ++m)
#pragma unroll
      for (int n = 0; n < 4; ++n)
#pragma unroll
        for (int r = 0; r < 4; ++r) {
          int prow = (w << 5) + m * 16 + (lg << 2) + r;
          int cb = ((n * 16 + li) << 1) ^ ((prow & 7) << 4);
          *(short*)((char*)lP + prow * 128 + cb) = f2bf(sc[m][n][r]);
        }
    asm volatile("s_waitcnt lgkmcnt(0)" ::: "memory");
    __builtin_amdgcn_sched_barrier(0);

    // PV: O(32x128) += P(32x64) @ V(64x128)
#pragma unroll
    for (int ks = 0; ks < 2; ++ks) {
      int prow0 = (w << 5) + li;
      int prow1 = prow0 + 16;
      int kb3 = ks * 64 + (lg << 4);
      s16x8 pf0 = *(const s16x8*)((char*)lP + prow0 * 128 + (kb3 ^ ((prow0 & 7) << 4)));
      s16x8 pf1 = *(const s16x8*)((char*)lP + prow1 * 128 + (kb3 ^ ((prow1 & 7) << 4)));
#pragma unroll
      for (int nd = 0; nd < 8; ++nd) {
        int d = nd * 16 + li;
        s16x8 vf = *(const s16x8*)((char*)lV + d * 144 +
                                   (kb3 ^ (((d >> 3) & 7) << 4)));
        o[0][nd] = __builtin_amdgcn_mfma_f32_16x16x32_bf16(pf0, vf, o[0][nd], 0, 0, 0);
        o[1][nd] = __builtin_amdgcn_mfma_f32_16x16x32_bf16(pf1, vf, o[1][nd], 0, 0, 0);
      }
    }
  }

  // normalize + store bf16 O (merged-head [B,S,D] layout)
#pragma unroll
  for (int m = 0; m < 2; ++m)
#pragma unroll
    for (int r = 0; r < 4; ++r) {
      float inv = 1.f / lrow[m][r];
      int row = q0 + (w << 5) + m * 16 + (lg << 2) + r;
      short* orow = Ob + hbase + (size_t)row * D_;
#pragma unroll
      for (int nd = 0; nd < 8; ++nd)
        orow[nd * 16 + li] = f2bf(o[m][nd][r] * inv);
    }
}

// ---------------- mask + residual + LayerNorm epilogue ----------------
__global__ __launch_bounds__(256) void ln_ep(const float* __restrict__ q,
                                             const short* __restrict__ Ob,
                                             const float* __restrict__ gam,
                                             const float* __restrict__ bet,
                                             float* __restrict__ out) {
  __shared__ float red[4][8];
  const int t = threadIdx.x;
  const int w = t >> 6, l = t & 63;
  const size_t off = (size_t)blockIdx.x * 1024 + t * 4;
  float4 qv = *(const float4*)(q + off);
  s16x4 ov = *(const s16x4*)(Ob + off);
  float oa[4] = {bf2f(ov[0]), bf2f(ov[1]), bf2f(ov[2]), bf2f(ov[3])};
  float qa[4] = {qv.x, qv.y, qv.z, qv.w};
  float s0 = 0, s1 = 0, s2 = 0, s3 = 0, s4 = 0, s5 = 0;
#pragma unroll
  for (int j = 0; j < 4; ++j) {
    s0 += fabsf(qa[j]);
    s1 += oa[j];
    s2 += qa[j];
    s3 += oa[j] * oa[j];
    s4 += oa[j] * qa[j];
    s5 += qa[j] * qa[j];
  }
#pragma unroll
  for (int d2 = 1; d2 < 64; d2 <<= 1) {
    s0 += __shfl_xor(s0, d2); s1 += __shfl_xor(s1, d2); s2 += __shfl_xor(s2, d2);
    s3 += __shfl_xor(s3, d2); s4 += __shfl_xor(s4, d2); s5 += __shfl_xor(s5, d2);
  }
  if (l == 0) {
    red[w][0] = s0; red[w][1] = s1; red[w][2] = s2;
    red[w][3] = s3; red[w][4] = s4; red[w][5] = s5;
  }
  __syncthreads();
  s0 = red[0][0] + red[1][0] + red[2][0] + red[3][0];
  s1 = red[0][1] + red[1][1] + red[2][1] + red[3][1];
  s2 = red[0][2] + red[1][2] + red[2][2] + red[3][2];
  s3 = red[0][3] + red[1][3] + red[2][3] + red[3][3];
  s4 = red[0][4] + red[1][4] + red[2][4] + red[3][4];
  s5 = red[0][5] + red[1][5] + red[2][5] + red[3][5];
  float msk = s0 > 0.f ? 1.f : 0.f;  // post-softmax query-row mask (==1 here)
  float sy = msk * s1 + s2;
  float sy2 = msk * s3 + 2.f * msk * s4 + s5;
  float mean = sy * (1.f / 1024.f);
  float var = sy2 * (1.f / 1024.f) - mean * mean;
  float inv = rsqrtf(fmaxf(var, 0.f) + 1e-8f);
  float4 gv = *(const float4*)(gam + t * 4);
  float4 bv = *(const float4*)(bet + t * 4);
  float4 rr;
  rr.x = (msk * oa[0] + qa[0] - mean) * inv * gv.x + bv.x;
  rr.y = (msk * oa[1] + qa[1] - mean) * inv * gv.y + bv.y;
  rr.z = (msk * oa[2] + qa[2] - mean) * inv * gv.z + bv.z;
  rr.w = (msk * oa[3] + qa[3] - mean) * inv * gv.w + bv.w;
  *(float4*)(out + off) = rr;
}

extern "C" void kernel_launch(void* const* d_in, const int* in_sizes, int n_in,
                              void* d_out, int out_size, void* d_ws, size_t ws_size,
                              hipStream_t stream) {
  const float* q   = (const float*)d_in[0];
  const float* k   = (const float*)d_in[1];
  const float* Wq  = (const float*)d_in[2];
  const float* bq  = (const float*)d_in[3];
  const float* Wk  = (const float*)d_in[4];
  const float* bk  = (const float*)d_in[5];
  const float* Wv  = (const float*)d_in[6];
  const float* bv  = (const float*)d_in[7];
  const float* gam = (const float*)d_in[8];
  const float* bet = (const float*)d_in[9];
  float* out = (float*)d_out;

  // workspace layout (bf16 bits as short). Total 166 MB.
  short* qb  = (short*)d_ws;        // 16M  queries bf16
  short* kb  = qb + 16777216;       // 16M  keys bf16
  short* wqb = kb + 16777216;       // 1M
  short* wkb = wqb + 1048576;       // 1M
  short* wvb = wkb + 1048576;       // 1M
  short* Qb  = wvb + 1048576;       // 16M
  short* Kb  = Qb + 16777216;       // 16M
  short* Vb  = Kb + 16777216;       // 16M
  short* Ob  = qb;                  // alias: qb dead after GEMM z=0 completes

  cvt_bf16<<<8192, 256, 0, stream>>>(q, qb, 2097152);
  cvt_bf16<<<8192, 256, 0, stream>>>(k, kb, 2097152);
  cvt_bf16<<<512, 256, 0, stream>>>(Wq, wqb, 131072);
  cvt_bf16<<<512, 256, 0, stream>>>(Wk, wkb, 131072);
  cvt_bf16<<<512, 256, 0, stream>>>(Wv, wvb, 131072);
  gemm_qkv<<<dim3(8, 128, 3), 256, 0, stream>>>(qb, kb, wqb, wkb, wvb,
                                                bq, bk, bv, Qb, Kb, Vb);
  attn_kernel<<<dim3(8, 128), 256, 0, stream>>>(Qb, Kb, Vb, Ob);
  ln_ep<<<16384, 256, 0, stream>>>(q, Ob, gam, bet, out);
}

// Round 5
// 486.236 us; speedup vs baseline: 1.0504x; 1.0504x over previous
//
#include <hip/hip_runtime.h>
#include <hip/hip_bf16.h>

// Problem: B=16, S=1024, D=1024, H=8, dh=128. M = B*S = 16384.
#define B_ 16
#define S_ 1024
#define D_ 1024
#define H_ 8

typedef __attribute__((ext_vector_type(4))) float f32x4;
typedef __attribute__((ext_vector_type(8))) short s16x8;
typedef __attribute__((ext_vector_type(4))) short s16x4;
typedef unsigned int u32;

static __device__ __forceinline__ short f2bf(float x) {
  union { __hip_bfloat16 h; short s; } cv;
  cv.h = __float2bfloat16(x);
  return cv.s;
}
static __device__ __forceinline__ float bf2f(short x) {
  union { float f; u32 u; } cv;
  cv.u = ((u32)(unsigned short)x) << 16;
  return cv.f;
}
static __device__ __forceinline__ float exp2_hw(float x) {
  float r;
  asm("v_exp_f32 %0, %1" : "=v"(r) : "v"(x));
  return r;
}
static __device__ __forceinline__ void async16(const void* g, void* l) {
  __builtin_amdgcn_global_load_lds((const __attribute__((address_space(1))) u32*)g,
                                   (__attribute__((address_space(3))) u32*)l, 16, 0, 0);
}

// log2(e)/sqrt(128): folded into Q so attn softmax uses exp2 directly.
#define QSCALE 0.12751741530f

// ---------------- f32 -> bf16 converts (fused launches) ----------------
__global__ __launch_bounds__(256) void cvt_qk(const float* __restrict__ q,
                                              const float* __restrict__ k,
                                              short* __restrict__ qb,
                                              short* __restrict__ kb) {
  int i = blockIdx.x * 256 + threadIdx.x;  // 16384 blocks -> 4.19M chunks
  const float* s;
  short* d;
  int j;
  if (i < 2097152) { s = q; d = qb; j = i; }
  else             { s = k; d = kb; j = i - 2097152; }
  const float4* s4 = (const float4*)s;
  float4 a = s4[2 * j], b = s4[2 * j + 1];
  s16x8 r;
  r[0] = f2bf(a.x); r[1] = f2bf(a.y); r[2] = f2bf(a.z); r[3] = f2bf(a.w);
  r[4] = f2bf(b.x); r[5] = f2bf(b.y); r[6] = f2bf(b.z); r[7] = f2bf(b.w);
  *(s16x8*)(d + (size_t)j * 8) = r;
}

__global__ __launch_bounds__(256) void cvt_w(const float* __restrict__ wq,
                                             const float* __restrict__ wk,
                                             const float* __restrict__ wv,
                                             short* __restrict__ dq,
                                             short* __restrict__ dk,
                                             short* __restrict__ dv) {
  int i = blockIdx.x * 256 + threadIdx.x;  // 1536 blocks
  const float* s;
  short* d;
  int j;
  if (i < 131072)      { s = wq; d = dq; j = i; }
  else if (i < 262144) { s = wk; d = dk; j = i - 131072; }
  else                 { s = wv; d = dv; j = i - 262144; }
  const float4* s4 = (const float4*)s;
  float4 a = s4[2 * j], b = s4[2 * j + 1];
  s16x8 r;
  r[0] = f2bf(a.x); r[1] = f2bf(a.y); r[2] = f2bf(a.z); r[3] = f2bf(a.w);
  r[4] = f2bf(b.x); r[5] = f2bf(b.y); r[6] = f2bf(b.z); r[7] = f2bf(b.w);
  *(s16x8*)(d + (size_t)j * 8) = r;
}

// ---------------- QKV projection GEMM: C = relu(A[M,K] @ W[N,K]^T + b) -----
// 128x128 tile, BK=64, 4 waves, 16x16x32 bf16 MFMA, global_load_lds w16
// staging with pre-swizzled source (rule 21). Q output pre-scaled by QSCALE.
__global__ __launch_bounds__(256, 2) void gemm_qkv(
    const short* __restrict__ qb, const short* __restrict__ kb,
    const short* __restrict__ wq, const short* __restrict__ wk,
    const short* __restrict__ wv, const float* __restrict__ bq,
    const float* __restrict__ bk, const float* __restrict__ bv,
    short* __restrict__ Qb, short* __restrict__ Kb, short* __restrict__ Vb) {
  __shared__ short lA[128 * 64];
  __shared__ short lB[128 * 64];
  const short* A; const short* W; const float* bias; short* C;
  float scl;
  switch (blockIdx.z) {
    case 0:  A = qb; W = wq; bias = bq; C = Qb; scl = QSCALE; break;
    case 1:  A = kb; W = wk; bias = bk; C = Kb; scl = 1.f; break;
    default: A = kb; W = wv; bias = bv; C = Vb; scl = 1.f; break;
  }
  const int t = threadIdx.x;
  const int w = t >> 6, l = t & 63, lg = l >> 4, li = l & 15;
  const int wr = w >> 1, wc = w & 1;
  const int m0 = blockIdx.y << 7, n0 = blockIdx.x << 7;

  f32x4 acc[4][4];
#pragma unroll
  for (int m = 0; m < 4; ++m)
#pragma unroll
    for (int n = 0; n < 4; ++n) acc[m][n] = {0.f, 0.f, 0.f, 0.f};

  const char* Ab = (const char*)A + (size_t)m0 * 2048;
  const char* Wb = (const char*)W + (size_t)n0 * 2048;

#pragma unroll 1
  for (int k0 = 0; k0 < 1024; k0 += 64) {
    __syncthreads();
#pragma unroll
    for (int it = 0; it < 4; ++it) {
      int e = it * 256 + t;
      int row = e >> 3;
      int sb = ((e & 7) << 4) ^ ((row & 7) << 4);
      async16(Ab + (size_t)row * 2048 + k0 * 2 + sb, (char*)lA + e * 16);
      async16(Wb + (size_t)row * 2048 + k0 * 2 + sb, (char*)lB + e * 16);
    }
    __syncthreads();
#pragma unroll
    for (int kk = 0; kk < 2; ++kk) {
      s16x8 af[4], bfr[4];
#pragma unroll
      for (int m = 0; m < 4; ++m) {
        int row = wr * 64 + m * 16 + li;
        af[m] = *(const s16x8*)((char*)lA + row * 128 +
                                ((kk * 64 + (lg << 4)) ^ ((row & 7) << 4)));
      }
#pragma unroll
      for (int n = 0; n < 4; ++n) {
        int row = wc * 64 + n * 16 + li;
        bfr[n] = *(const s16x8*)((char*)lB + row * 128 +
                                 ((kk * 64 + (lg << 4)) ^ ((row & 7) << 4)));
      }
#pragma unroll
      for (int m = 0; m < 4; ++m)
#pragma unroll
        for (int n = 0; n < 4; ++n)
          acc[m][n] = __builtin_amdgcn_mfma_f32_16x16x32_bf16(af[m], bfr[n],
                                                              acc[m][n], 0, 0, 0);
    }
  }
#pragma unroll
  for (int n = 0; n < 4; ++n) {
    int col = n0 + wc * 64 + n * 16 + li;
    float bb = bias[col];
#pragma unroll
    for (int m = 0; m < 4; ++m) {
      int row0 = m0 + wr * 64 + m * 16 + (lg << 2);
#pragma unroll
      for (int r = 0; r < 4; ++r) {
        float v = acc[m][n][r] + bb;
        v = (v > 0.f ? v : 0.f) * scl;
        C[(size_t)(row0 + r) * 1024 + col] = f2bf(v);
      }
    }
  }
}

// ---------------- Flash attention ----------------
// Flat grid 1024, XCD-swizzled: all 8 q-blocks of a (b,h) share one XCD's L2.
// 4 waves; wave owns 32 q-rows; K/V tiles of 64 rows.
// Reg-staged K+V, issue-early/write-late (T14): loads for kt+1 issue after the
// post-staging barrier so the compiler's vmcnt(0) drain never stalls on them.
// lK: swizzled rows (256B). lV[d][k]: stride 176B -> conflict-free transposed
// staging via packed b32 writes. lP: swizzled 128B rows (wave-private).
__global__ __launch_bounds__(256, 2) void attn_kernel(
    const short* __restrict__ Qb, const short* __restrict__ Kb,
    const short* __restrict__ Vb, short* __restrict__ Ob) {
  __shared__ short lK[64 * 128];   // 16 KB
  __shared__ short lV[128 * 88];   // 22 KB, row stride 176B
  __shared__ short lP[128 * 64];   // 16 KB

  const int t = threadIdx.x;
  const int w = t >> 6, l = t & 63, lg = l >> 4, li = l & 15;
  const int wgid = blockIdx.x;
  const int bh = ((wgid & 7) << 4) + (wgid >> 6);
  const int q0 = ((wgid >> 3) & 7) << 7;
  const int b = bh >> 3, h = bh & 7;
  const size_t hbase = (size_t)b * (S_ * D_) + h * 128;
  const short* Kh = Kb + hbase;
  const short* Vh = Vb + hbase;

  s16x8 qf[2][4];
#pragma unroll
  for (int m = 0; m < 2; ++m)
#pragma unroll
    for (int kk = 0; kk < 4; ++kk) {
      int row = q0 + (w << 5) + m * 16 + li;
      qf[m][kk] = *(const s16x8*)(Qb + hbase + (size_t)row * D_ + kk * 32 + (lg << 3));
    }

  f32x4 o[2][8];
#pragma unroll
  for (int m = 0; m < 2; ++m)
#pragma unroll
    for (int nd = 0; nd < 8; ++nd) o[m][nd] = {0.f, 0.f, 0.f, 0.f};
  float mrow[2][4], lrow[2][4];
#pragma unroll
  for (int m = 0; m < 2; ++m)
#pragma unroll
    for (int r = 0; r < 4; ++r) { mrow[m][r] = -1e30f; lrow[m][r] = 0.f; }

  // staging registers for tile kt (K: 4 chunks; V: 2x2 rows)
  s16x8 kreg[4], vr0[2], vr1[2];
#define LOADT(KT)                                                              \
  {                                                                            \
    _Pragma("unroll") for (int it = 0; it < 4; ++it) {                         \
      int e = it * 256 + t;                                                    \
      kreg[it] = *(const s16x8*)(Kh + (size_t)((KT)*64 + (e >> 4)) * 1024 +    \
                                 (e & 15) * 8);                                \
    }                                                                          \
    _Pragma("unroll") for (int vit = 0; vit < 2; ++vit) {                      \
      int e2 = vit * 256 + t;                                                  \
      int k0 = (e2 & 31) * 2, d0 = (e2 >> 5) * 8;                              \
      vr0[vit] = *(const s16x8*)(Vh + (size_t)((KT)*64 + k0) * 1024 + d0);     \
      vr1[vit] = *(const s16x8*)(Vh + (size_t)((KT)*64 + k0 + 1) * 1024 + d0); \
    }                                                                          \
  }

  LOADT(0);

#pragma unroll 1
  for (int kt = 0; kt < 16; ++kt) {
    __syncthreads();  // all waves done reading LDS tile kt-1
    // stage K (swizzled b128 writes)
#pragma unroll
    for (int it = 0; it < 4; ++it) {
      int e = it * 256 + t;
      int kr = e >> 4, kc = e & 15;
      *(s16x8*)((char*)lK + kr * 256 + ((kc * 16) ^ ((kr & 7) << 4))) = kreg[it];
    }
    // stage V transposed: packed (k,k+1) b32 writes, conflict-free by stride
#pragma unroll
    for (int vit = 0; vit < 2; ++vit) {
      int e2 = vit * 256 + t;
      int k0 = (e2 & 31) * 2, d0 = (e2 >> 5) * 8;
#pragma unroll
      for (int j = 0; j < 8; ++j) {
        u32 pk = (u32)(unsigned short)vr0[vit][j] |
                 ((u32)(unsigned short)vr1[vit][j] << 16);
        *(u32*)((char*)lV + (d0 + j) * 176 + k0 * 2) = pk;
      }
    }
    __syncthreads();  // staging visible; no vmem outstanding at this drain
    if (kt < 15) LOADT(kt + 1);  // prefetch overlaps QK+softmax+PV

    // QK^T (Q pre-scaled: scores already in log2-units)
    f32x4 sc[2][4];
#pragma unroll
    for (int m = 0; m < 2; ++m)
#pragma unroll
      for (int n = 0; n < 4; ++n) sc[m][n] = {0.f, 0.f, 0.f, 0.f};
#pragma unroll
    for (int kk = 0; kk < 4; ++kk)
#pragma unroll
      for (int n = 0; n < 4; ++n) {
        int krow = n * 16 + li;
        s16x8 kf = *(const s16x8*)((char*)lK + krow * 256 +
                                   ((kk * 64 + (lg << 4)) ^ ((krow & 7) << 4)));
        sc[0][n] = __builtin_amdgcn_mfma_f32_16x16x32_bf16(qf[0][kk], kf, sc[0][n], 0, 0, 0);
        sc[1][n] = __builtin_amdgcn_mfma_f32_16x16x32_bf16(qf[1][kk], kf, sc[1][n], 0, 0, 0);
      }

    // tile max + defer-max (T13, THR = 8*log2e ~= 11.5)
    float tm[2][4];
    bool skip = true;
#pragma unroll
    for (int m = 0; m < 2; ++m)
#pragma unroll
      for (int r = 0; r < 4; ++r) {
        float v = fmaxf(fmaxf(sc[m][0][r], sc[m][1][r]),
                        fmaxf(sc[m][2][r], sc[m][3][r]));
        v = fmaxf(v, __shfl_xor(v, 1));
        v = fmaxf(v, __shfl_xor(v, 2));
        v = fmaxf(v, __shfl_xor(v, 4));
        v = fmaxf(v, __shfl_xor(v, 8));
        tm[m][r] = v;
        skip = skip && (v <= mrow[m][r] + 11.5f);
      }
    if (!__all(skip)) {
#pragma unroll
      for (int m = 0; m < 2; ++m)
#pragma unroll
        for (int r = 0; r < 4; ++r) {
          float mnew = fmaxf(mrow[m][r], tm[m][r]);
          float fsc = exp2_hw(mrow[m][r] - mnew);
          mrow[m][r] = mnew;
          lrow[m][r] *= fsc;
#pragma unroll
          for (int nd = 0; nd < 8; ++nd) o[m][nd][r] *= fsc;
        }
    }
#pragma unroll
    for (int m = 0; m < 2; ++m)
#pragma unroll
      for (int r = 0; r < 4; ++r) {
        float ps = 0.f;
#pragma unroll
        for (int n = 0; n < 4; ++n) {
          float p = exp2_hw(sc[m][n][r] - mrow[m][r]);
          sc[m][n][r] = p;
          ps += p;
        }
        ps += __shfl_xor(ps, 1);
        ps += __shfl_xor(ps, 2);
        ps += __shfl_xor(ps, 4);
        ps += __shfl_xor(ps, 8);
        lrow[m][r] += ps;
      }

    // write P (bf16) to wave-private lP slice, swizzled
#pragma unroll
    for (int m = 0; m < 2; ++m)
#pragma unroll
      for (int n = 0; n < 4; ++n)
#pragma unroll
        for (int r = 0; r < 4; ++r) {
          int prow = (w << 5) + m * 16 + (lg << 2) + r;
          int cb = ((n * 16 + li) << 1) ^ ((prow & 7) << 4);
          *(short*)((char*)lP + prow * 128 + cb) = f2bf(sc[m][n][r]);
        }
    asm volatile("s_waitcnt lgkmcnt(0)" ::: "memory");
    __builtin_amdgcn_sched_barrier(0);

    // PV: O(32x128) += P(32x64) @ V(64x128)
#pragma unroll
    for (int ks = 0; ks < 2; ++ks) {
      int prow0 = (w << 5) + li;
      int prow1 = prow0 + 16;
      int kb3 = ks * 64 + (lg << 4);
      s16x8 pf0 = *(const s16x8*)((char*)lP + prow0 * 128 + (kb3 ^ ((prow0 & 7) << 4)));
      s16x8 pf1 = *(const s16x8*)((char*)lP + prow1 * 128 + (kb3 ^ ((prow1 & 7) << 4)));
#pragma unroll
      for (int nd = 0; nd < 8; ++nd) {
        int d = nd * 16 + li;
        s16x8 vf = *(const s16x8*)((char*)lV + d * 176 + kb3);
        o[0][nd] = __builtin_amdgcn_mfma_f32_16x16x32_bf16(pf0, vf, o[0][nd], 0, 0, 0);
        o[1][nd] = __builtin_amdgcn_mfma_f32_16x16x32_bf16(pf1, vf, o[1][nd], 0, 0, 0);
      }
    }
  }
#undef LOADT

  // normalize + store bf16 O (merged-head [B,S,D] layout)
#pragma unroll
  for (int m = 0; m < 2; ++m)
#pragma unroll
    for (int r = 0; r < 4; ++r) {
      float inv = 1.f / lrow[m][r];
      int row = q0 + (w << 5) + m * 16 + (lg << 2) + r;
      short* orow = Ob + hbase + (size_t)row * D_;
#pragma unroll
      for (int nd = 0; nd < 8; ++nd)
        orow[nd * 16 + li] = f2bf(o[m][nd][r] * inv);
    }
}

// ---------------- mask + residual + LayerNorm epilogue ----------------
__global__ __launch_bounds__(256) void ln_ep(const float* __restrict__ q,
                                             const short* __restrict__ Ob,
                                             const float* __restrict__ gam,
                                             const float* __restrict__ bet,
                                             float* __restrict__ out) {
  __shared__ float red[4][8];
  const int t = threadIdx.x;
  const int w = t >> 6, l = t & 63;
  const size_t off = (size_t)blockIdx.x * 1024 + t * 4;
  float4 qv = *(const float4*)(q + off);
  s16x4 ov = *(const s16x4*)(Ob + off);
  float oa[4] = {bf2f(ov[0]), bf2f(ov[1]), bf2f(ov[2]), bf2f(ov[3])};
  float qa[4] = {qv.x, qv.y, qv.z, qv.w};
  float s0 = 0, s1 = 0, s2 = 0, s3 = 0, s4 = 0, s5 = 0;
#pragma unroll
  for (int j = 0; j < 4; ++j) {
    s0 += fabsf(qa[j]);
    s1 += oa[j];
    s2 += qa[j];
    s3 += oa[j] * oa[j];
    s4 += oa[j] * qa[j];
    s5 += qa[j] * qa[j];
  }
#pragma unroll
  for (int d2 = 1; d2 < 64; d2 <<= 1) {
    s0 += __shfl_xor(s0, d2); s1 += __shfl_xor(s1, d2); s2 += __shfl_xor(s2, d2);
    s3 += __shfl_xor(s3, d2); s4 += __shfl_xor(s4, d2); s5 += __shfl_xor(s5, d2);
  }
  if (l == 0) {
    red[w][0] = s0; red[w][1] = s1; red[w][2] = s2;
    red[w][3] = s3; red[w][4] = s4; red[w][5] = s5;
  }
  __syncthreads();
  s0 = red[0][0] + red[1][0] + red[2][0] + red[3][0];
  s1 = red[0][1] + red[1][1] + red[2][1] + red[3][1];
  s2 = red[0][2] + red[1][2] + red[2][2] + red[3][2];
  s3 = red[0][3] + red[1][3] + red[2][3] + red[3][3];
  s4 = red[0][4] + red[1][4] + red[2][4] + red[3][4];
  s5 = red[0][5] + red[1][5] + red[2][5] + red[3][5];
  float msk = s0 > 0.f ? 1.f : 0.f;  // post-softmax query-row mask (==1 here)
  float sy = msk * s1 + s2;
  float sy2 = msk * s3 + 2.f * msk * s4 + s5;
  float mean = sy * (1.f / 1024.f);
  float var = sy2 * (1.f / 1024.f) - mean * mean;
  float inv = rsqrtf(fmaxf(var, 0.f) + 1e-8f);
  float4 gv = *(const float4*)(gam + t * 4);
  float4 bv = *(const float4*)(bet + t * 4);
  float4 rr;
  rr.x = (msk * oa[0] + qa[0] - mean) * inv * gv.x + bv.x;
  rr.y = (msk * oa[1] + qa[1] - mean) * inv * gv.y + bv.y;
  rr.z = (msk * oa[2] + qa[2] - mean) * inv * gv.z + bv.z;
  rr.w = (msk * oa[3] + qa[3] - mean) * inv * gv.w + bv.w;
  *(float4*)(out + off) = rr;
}

extern "C" void kernel_launch(void* const* d_in, const int* in_sizes, int n_in,
                              void* d_out, int out_size, void* d_ws, size_t ws_size,
                              hipStream_t stream) {
  const float* q   = (const float*)d_in[0];
  const float* k   = (const float*)d_in[1];
  const float* Wq  = (const float*)d_in[2];
  const float* bq  = (const float*)d_in[3];
  const float* Wk  = (const float*)d_in[4];
  const float* bk  = (const float*)d_in[5];
  const float* Wv  = (const float*)d_in[6];
  const float* bv  = (const float*)d_in[7];
  const float* gam = (const float*)d_in[8];
  const float* bet = (const float*)d_in[9];
  float* out = (float*)d_out;

  short* qb  = (short*)d_ws;        // 16M  queries bf16
  short* kb  = qb + 16777216;       // 16M  keys bf16
  short* wqb = kb + 16777216;       // 1M
  short* wkb = wqb + 1048576;       // 1M
  short* wvb = wkb + 1048576;       // 1M
  short* Qb  = wvb + 1048576;       // 16M (pre-scaled by QSCALE)
  short* Kb  = Qb + 16777216;       // 16M
  short* Vb  = Kb + 16777216;       // 16M
  short* Ob  = qb;                  // alias: qb dead after GEMM z=0 completes

  cvt_qk<<<16384, 256, 0, stream>>>(q, k, qb, kb);
  cvt_w<<<1536, 256, 0, stream>>>(Wq, Wk, Wv, wqb, wkb, wvb);
  gemm_qkv<<<dim3(8, 128, 3), 256, 0, stream>>>(qb, kb, wqb, wkb, wvb,
                                                bq, bk, bv, Qb, Kb, Vb);
  attn_kernel<<<1024, 256, 0, stream>>>(Qb, Kb, Vb, Ob);
  ln_ep<<<16384, 256, 0, stream>>>(q, Ob, gam, bet, out);
}

// Round 6
// 464.379 us; speedup vs baseline: 1.0998x; 1.0471x over previous
//
#include <hip/hip_runtime.h>
#include <hip/hip_bf16.h>

// Problem: B=16, S=1024, D=1024, H=8, dh=128. M = B*S = 16384.
#define B_ 16
#define S_ 1024
#define D_ 1024
#define H_ 8

typedef __attribute__((ext_vector_type(4))) float f32x4;
typedef __attribute__((ext_vector_type(8))) short s16x8;
typedef __attribute__((ext_vector_type(4))) short s16x4;
typedef unsigned int u32;

static __device__ __forceinline__ short f2bf(float x) {
  union { __hip_bfloat16 h; short s; } cv;
  cv.h = __float2bfloat16(x);
  return cv.s;
}
static __device__ __forceinline__ float bf2f(short x) {
  union { float f; u32 u; } cv;
  cv.u = ((u32)(unsigned short)x) << 16;
  return cv.f;
}
static __device__ __forceinline__ float exp2_hw(float x) {
  float r;
  asm("v_exp_f32 %0, %1" : "=v"(r) : "v"(x));
  return r;
}
static __device__ __forceinline__ void async16(const void* g, void* l) {
  __builtin_amdgcn_global_load_lds((const __attribute__((address_space(1))) u32*)g,
                                   (__attribute__((address_space(3))) u32*)l, 16, 0, 0);
}

// log2(e)/sqrt(128): folded into Q so attn softmax uses exp2 directly.
#define QSCALE 0.12751741530f

// ---------------- f32 -> bf16 converts (fused launches) ----------------
__global__ __launch_bounds__(256) void cvt_qk(const float* __restrict__ q,
                                              const float* __restrict__ k,
                                              short* __restrict__ qb,
                                              short* __restrict__ kb) {
  int i = blockIdx.x * 256 + threadIdx.x;
  const float* s;
  short* d;
  int j;
  if (i < 2097152) { s = q; d = qb; j = i; }
  else             { s = k; d = kb; j = i - 2097152; }
  const float4* s4 = (const float4*)s;
  float4 a = s4[2 * j], b = s4[2 * j + 1];
  s16x8 r;
  r[0] = f2bf(a.x); r[1] = f2bf(a.y); r[2] = f2bf(a.z); r[3] = f2bf(a.w);
  r[4] = f2bf(b.x); r[5] = f2bf(b.y); r[6] = f2bf(b.z); r[7] = f2bf(b.w);
  *(s16x8*)(d + (size_t)j * 8) = r;
}

__global__ __launch_bounds__(256) void cvt_w(const float* __restrict__ wq,
                                             const float* __restrict__ wk,
                                             const float* __restrict__ wv,
                                             short* __restrict__ dq,
                                             short* __restrict__ dk,
                                             short* __restrict__ dv) {
  int i = blockIdx.x * 256 + threadIdx.x;
  const float* s;
  short* d;
  int j;
  if (i < 131072)      { s = wq; d = dq; j = i; }
  else if (i < 262144) { s = wk; d = dk; j = i - 131072; }
  else                 { s = wv; d = dv; j = i - 262144; }
  const float4* s4 = (const float4*)s;
  float4 a = s4[2 * j], b = s4[2 * j + 1];
  s16x8 r;
  r[0] = f2bf(a.x); r[1] = f2bf(a.y); r[2] = f2bf(a.z); r[3] = f2bf(a.w);
  r[4] = f2bf(b.x); r[5] = f2bf(b.y); r[6] = f2bf(b.z); r[7] = f2bf(b.w);
  *(s16x8*)(d + (size_t)j * 8) = r;
}

// ---------------- QKV projection GEMM, 256x256 8-phase ----------------
// C = relu(A[M,K] @ W[N,K]^T + b). 8 waves (2Mx4N), BK=64 split into kk halves.
// LDS 128KB: [buf2][op A/B][kk][256 rows x 32 cols bf16]. Staging: 1 half
// (2x global_load_lds w16/thread) per phase into the region dead since the
// previous phase. Counted vmcnt(8) at even phases only (never 0 in main loop);
// tail drains 8->4->0. Swizzle: byte ^= ((row&3)<<4), both-sides (rule 21).
__global__ __launch_bounds__(512, 1) void gemm_qkv(
    const short* __restrict__ qb, const short* __restrict__ kb,
    const short* __restrict__ wq, const short* __restrict__ wk,
    const short* __restrict__ wv, const float* __restrict__ bq,
    const float* __restrict__ bk, const float* __restrict__ bv,
    short* __restrict__ Qb, short* __restrict__ Kb, short* __restrict__ Vb) {
  __shared__ short LDS[65536];  // 128 KiB
  const short* A; const short* W; const float* bias; short* C;
  float scl;
  switch (blockIdx.z) {
    case 0:  A = qb; W = wq; bias = bq; C = Qb; scl = QSCALE; break;
    case 1:  A = kb; W = wk; bias = bk; C = Kb; scl = 1.f; break;
    default: A = kb; W = wv; bias = bv; C = Vb; scl = 1.f; break;
  }
  const int t = threadIdx.x;
  const int w = t >> 6, l = t & 63, lg = l >> 4, li = l & 15;
  const int wr = w >> 2, wc = w & 3;  // 2 x 4 wave grid
  const int swz = ((blockIdx.x & 7) << 5) + (blockIdx.x >> 3);  // XCD swizzle
  const int m0 = (swz >> 2) << 8;
  const int n0 = (swz & 3) << 8;

  f32x4 acc[8][4];
#pragma unroll
  for (int m = 0; m < 8; ++m)
#pragma unroll
    for (int n = 0; n < 4; ++n) acc[m][n] = {0.f, 0.f, 0.f, 0.f};

  // stage one half-tile (op,kk) of K-tile kt into buf
  auto STAGE = [&](int kt, int buf, int op, int kk) {
    const short* src = op ? W : A;
    const int rb = op ? n0 : m0;
    char* dst = (char*)LDS + ((((buf << 1) | op) << 1) | kk) * 16384;
#pragma unroll
    for (int j = 0; j < 2; ++j) {
      int e = j * 512 + t;
      int row = e >> 2, ch = e & 3;
      size_t sb = (size_t)(rb + row) * 2048 + kt * 128 + kk * 64 +
                  ((ch ^ (row & 3)) << 4);
      async16((const char*)src + sb, dst + e * 16);
    }
  };
  const int swzRD = (lg << 4);  // XORed with ((row&3)<<4) per read; row&3==li&3
  auto RDA = [&](int buf, int kk, int m) -> s16x8 {
    int row = wr * 128 + m * 16 + li;
    const char* p = (char*)LDS + ((((buf << 1) | 0) << 1) | kk) * 16384 +
                    row * 64 + (swzRD ^ ((li & 3) << 4));
    return *(const s16x8*)p;
  };
  auto RDB = [&](int buf, int kk, int n) -> s16x8 {
    int row = wc * 64 + n * 16 + li;
    const char* p = (char*)LDS + ((((buf << 1) | 1) << 1) | kk) * 16384 +
                    row * 64 + (swzRD ^ ((li & 3) << 4));
    return *(const s16x8*)p;
  };

  s16x8 bf0, bf1, bf2, bf3;

#define MFMA16(MOFF)                                                           \
  {                                                                            \
    _Pragma("unroll") for (int mm = 0; mm < 4; ++mm) {                         \
      acc[(MOFF) + mm][0] = __builtin_amdgcn_mfma_f32_16x16x32_bf16(           \
          af[mm], bf0, acc[(MOFF) + mm][0], 0, 0, 0);                          \
      acc[(MOFF) + mm][1] = __builtin_amdgcn_mfma_f32_16x16x32_bf16(           \
          af[mm], bf1, acc[(MOFF) + mm][1], 0, 0, 0);                          \
      acc[(MOFF) + mm][2] = __builtin_amdgcn_mfma_f32_16x16x32_bf16(           \
          af[mm], bf2, acc[(MOFF) + mm][2], 0, 0, 0);                          \
      acc[(MOFF) + mm][3] = __builtin_amdgcn_mfma_f32_16x16x32_bf16(           \
          af[mm], bf3, acc[(MOFF) + mm][3], 0, 0, 0);                          \
    }                                                                          \
  }

// one phase: ds-reads, stage issue, counted vmcnt, barrier, lgkm0, 16 MFMA
#define PHASE(CBUF, CKK, MOFF, ODDP, DOSTAGE, SKT, SBUF, SOP, SKK, WAITN)      \
  {                                                                            \
    s16x8 af[4];                                                               \
    _Pragma("unroll") for (int mm = 0; mm < 4; ++mm)                           \
        af[mm] = RDA(CBUF, CKK, (MOFF) + mm);                                  \
    if (ODDP) {                                                                \
      bf0 = RDB(CBUF, CKK, 0); bf1 = RDB(CBUF, CKK, 1);                        \
      bf2 = RDB(CBUF, CKK, 2); bf3 = RDB(CBUF, CKK, 3);                        \
    }                                                                          \
    if (DOSTAGE) STAGE(SKT, SBUF, SOP, SKK);                                   \
    if ((WAITN) == 8) asm volatile("s_waitcnt vmcnt(8)" ::: "memory");         \
    if ((WAITN) == 4) asm volatile("s_waitcnt vmcnt(4)" ::: "memory");         \
    if ((WAITN) == 0) asm volatile("s_waitcnt vmcnt(0)" ::: "memory");         \
    __builtin_amdgcn_s_barrier();                                              \
    asm volatile("s_waitcnt lgkmcnt(0)" ::: "memory");                         \
    __builtin_amdgcn_sched_barrier(0);                                         \
    __builtin_amdgcn_s_setprio(1);                                             \
    MFMA16(MOFF);                                                              \
    __builtin_amdgcn_s_setprio(0);                                             \
    __builtin_amdgcn_s_barrier();                                              \
  }

  // prologue: K0 all 4 halves + K1 kk0 halves (6 stages); wait oldest 2
  STAGE(0, 0, 0, 0); STAGE(0, 0, 1, 0);
  STAGE(0, 0, 0, 1); STAGE(0, 0, 1, 1);
  STAGE(1, 1, 0, 0); STAGE(1, 1, 1, 0);
  asm volatile("s_waitcnt vmcnt(8)" ::: "memory");
  __builtin_amdgcn_s_barrier();

#pragma unroll 1
  for (int j = 0; j < 7; ++j) {
    const int k1 = 2 * j + 1, k2 = 2 * j + 2, k3 = 2 * j + 3;
    PHASE(0, 0, 0, 1, 1, k1, 1, 0, 1, -1)  // P1 stage A-kk1 of K(2j+1)
    PHASE(0, 0, 4, 0, 1, k1, 1, 1, 1, 8)   // P2 stage B-kk1
    PHASE(0, 1, 0, 1, 1, k2, 0, 0, 0, -1)  // P3 stage A-kk0 of K(2j+2)
    PHASE(0, 1, 4, 0, 1, k2, 0, 1, 0, 8)   // P4
    PHASE(1, 0, 0, 1, 1, k2, 0, 0, 1, -1)  // P5 stage A-kk1 of K(2j+2)
    PHASE(1, 0, 4, 0, 1, k2, 0, 1, 1, 8)   // P6
    PHASE(1, 1, 0, 1, 1, k3, 1, 0, 0, -1)  // P7 stage A-kk0 of K(2j+3)
    PHASE(1, 1, 4, 0, 1, k3, 1, 1, 0, 8)   // P8
  }
  // tail iteration (K14/K15 compute): only K15-kk1 staging remains; drain
  PHASE(0, 0, 0, 1, 1, 15, 1, 0, 1, -1)
  PHASE(0, 0, 4, 0, 1, 15, 1, 1, 1, 8)
  PHASE(0, 1, 0, 1, 0, 0, 0, 0, 0, -1)
  PHASE(0, 1, 4, 0, 0, 0, 0, 0, 0, 4)
  PHASE(1, 0, 0, 1, 0, 0, 0, 0, 0, -1)
  PHASE(1, 0, 4, 0, 0, 0, 0, 0, 0, 0)
  PHASE(1, 1, 0, 1, 0, 0, 0, 0, 0, -1)
  PHASE(1, 1, 4, 0, 0, 0, 0, 0, 0, -1)
#undef PHASE
#undef MFMA16

  // epilogue: bias + relu + scale, bf16 store
#pragma unroll
  for (int n = 0; n < 4; ++n) {
    int col = n0 + wc * 64 + n * 16 + li;
    float bb = bias[col];
#pragma unroll
    for (int m = 0; m < 8; ++m) {
      int row0 = m0 + wr * 128 + m * 16 + (lg << 2);
#pragma unroll
      for (int r = 0; r < 4; ++r) {
        float v = acc[m][n][r] + bb;
        v = (v > 0.f ? v : 0.f) * scl;
        C[(size_t)(row0 + r) * 1024 + col] = f2bf(v);
      }
    }
  }
}

// ---------------- Flash attention (unchanged from R5) ----------------
__global__ __launch_bounds__(256, 2) void attn_kernel(
    const short* __restrict__ Qb, const short* __restrict__ Kb,
    const short* __restrict__ Vb, short* __restrict__ Ob) {
  __shared__ short lK[64 * 128];
  __shared__ short lV[128 * 88];
  __shared__ short lP[128 * 64];

  const int t = threadIdx.x;
  const int w = t >> 6, l = t & 63, lg = l >> 4, li = l & 15;
  const int wgid = blockIdx.x;
  const int bh = ((wgid & 7) << 4) + (wgid >> 6);
  const int q0 = ((wgid >> 3) & 7) << 7;
  const int b = bh >> 3, h = bh & 7;
  const size_t hbase = (size_t)b * (S_ * D_) + h * 128;
  const short* Kh = Kb + hbase;
  const short* Vh = Vb + hbase;

  s16x8 qf[2][4];
#pragma unroll
  for (int m = 0; m < 2; ++m)
#pragma unroll
    for (int kk = 0; kk < 4; ++kk) {
      int row = q0 + (w << 5) + m * 16 + li;
      qf[m][kk] = *(const s16x8*)(Qb + hbase + (size_t)row * D_ + kk * 32 + (lg << 3));
    }

  f32x4 o[2][8];
#pragma unroll
  for (int m = 0; m < 2; ++m)
#pragma unroll
    for (int nd = 0; nd < 8; ++nd) o[m][nd] = {0.f, 0.f, 0.f, 0.f};
  float mrow[2][4], lrow[2][4];
#pragma unroll
  for (int m = 0; m < 2; ++m)
#pragma unroll
    for (int r = 0; r < 4; ++r) { mrow[m][r] = -1e30f; lrow[m][r] = 0.f; }

  s16x8 kreg[4], vr0[2], vr1[2];
#define LOADT(KT)                                                              \
  {                                                                            \
    _Pragma("unroll") for (int it = 0; it < 4; ++it) {                         \
      int e = it * 256 + t;                                                    \
      kreg[it] = *(const s16x8*)(Kh + (size_t)((KT)*64 + (e >> 4)) * 1024 +    \
                                 (e & 15) * 8);                                \
    }                                                                          \
    _Pragma("unroll") for (int vit = 0; vit < 2; ++vit) {                      \
      int e2 = vit * 256 + t;                                                  \
      int k0 = (e2 & 31) * 2, d0 = (e2 >> 5) * 8;                              \
      vr0[vit] = *(const s16x8*)(Vh + (size_t)((KT)*64 + k0) * 1024 + d0);     \
      vr1[vit] = *(const s16x8*)(Vh + (size_t)((KT)*64 + k0 + 1) * 1024 + d0); \
    }                                                                          \
  }

  LOADT(0);

#pragma unroll 1
  for (int kt = 0; kt < 16; ++kt) {
    __syncthreads();
#pragma unroll
    for (int it = 0; it < 4; ++it) {
      int e = it * 256 + t;
      int kr = e >> 4, kc = e & 15;
      *(s16x8*)((char*)lK + kr * 256 + ((kc * 16) ^ ((kr & 7) << 4))) = kreg[it];
    }
#pragma unroll
    for (int vit = 0; vit < 2; ++vit) {
      int e2 = vit * 256 + t;
      int k0 = (e2 & 31) * 2, d0 = (e2 >> 5) * 8;
#pragma unroll
      for (int j = 0; j < 8; ++j) {
        u32 pk = (u32)(unsigned short)vr0[vit][j] |
                 ((u32)(unsigned short)vr1[vit][j] << 16);
        *(u32*)((char*)lV + (d0 + j) * 176 + k0 * 2) = pk;
      }
    }
    __syncthreads();
    if (kt < 15) LOADT(kt + 1);

    f32x4 sc[2][4];
#pragma unroll
    for (int m = 0; m < 2; ++m)
#pragma unroll
      for (int n = 0; n < 4; ++n) sc[m][n] = {0.f, 0.f, 0.f, 0.f};
#pragma unroll
    for (int kk = 0; kk < 4; ++kk)
#pragma unroll
      for (int n = 0; n < 4; ++n) {
        int krow = n * 16 + li;
        s16x8 kf = *(const s16x8*)((char*)lK + krow * 256 +
                                   ((kk * 64 + (lg << 4)) ^ ((krow & 7) << 4)));
        sc[0][n] = __builtin_amdgcn_mfma_f32_16x16x32_bf16(qf[0][kk], kf, sc[0][n], 0, 0, 0);
        sc[1][n] = __builtin_amdgcn_mfma_f32_16x16x32_bf16(qf[1][kk], kf, sc[1][n], 0, 0, 0);
      }

    float tm[2][4];
    bool skip = true;
#pragma unroll
    for (int m = 0; m < 2; ++m)
#pragma unroll
      for (int r = 0; r < 4; ++r) {
        float v = fmaxf(fmaxf(sc[m][0][r], sc[m][1][r]),
                        fmaxf(sc[m][2][r], sc[m][3][r]));
        v = fmaxf(v, __shfl_xor(v, 1));
        v = fmaxf(v, __shfl_xor(v, 2));
        v = fmaxf(v, __shfl_xor(v, 4));
        v = fmaxf(v, __shfl_xor(v, 8));
        tm[m][r] = v;
        skip = skip && (v <= mrow[m][r] + 11.5f);
      }
    if (!__all(skip)) {
#pragma unroll
      for (int m = 0; m < 2; ++m)
#pragma unroll
        for (int r = 0; r < 4; ++r) {
          float mnew = fmaxf(mrow[m][r], tm[m][r]);
          float fsc = exp2_hw(mrow[m][r] - mnew);
          mrow[m][r] = mnew;
          lrow[m][r] *= fsc;
#pragma unroll
          for (int nd = 0; nd < 8; ++nd) o[m][nd][r] *= fsc;
        }
    }
#pragma unroll
    for (int m = 0; m < 2; ++m)
#pragma unroll
      for (int r = 0; r < 4; ++r) {
        float ps = 0.f;
#pragma unroll
        for (int n = 0; n < 4; ++n) {
          float p = exp2_hw(sc[m][n][r] - mrow[m][r]);
          sc[m][n][r] = p;
          ps += p;
        }
        ps += __shfl_xor(ps, 1);
        ps += __shfl_xor(ps, 2);
        ps += __shfl_xor(ps, 4);
        ps += __shfl_xor(ps, 8);
        lrow[m][r] += ps;
      }

#pragma unroll
    for (int m = 0; m < 2; ++m)
#pragma unroll
      for (int n = 0; n < 4; ++n)
#pragma unroll
        for (int r = 0; r < 4; ++r) {
          int prow = (w << 5) + m * 16 + (lg << 2) + r;
          int cb = ((n * 16 + li) << 1) ^ ((prow & 7) << 4);
          *(short*)((char*)lP + prow * 128 + cb) = f2bf(sc[m][n][r]);
        }
    asm volatile("s_waitcnt lgkmcnt(0)" ::: "memory");
    __builtin_amdgcn_sched_barrier(0);

#pragma unroll
    for (int ks = 0; ks < 2; ++ks) {
      int prow0 = (w << 5) + li;
      int prow1 = prow0 + 16;
      int kb3 = ks * 64 + (lg << 4);
      s16x8 pf0 = *(const s16x8*)((char*)lP + prow0 * 128 + (kb3 ^ ((prow0 & 7) << 4)));
      s16x8 pf1 = *(const s16x8*)((char*)lP + prow1 * 128 + (kb3 ^ ((prow1 & 7) << 4)));
#pragma unroll
      for (int nd = 0; nd < 8; ++nd) {
        int d = nd * 16 + li;
        s16x8 vf = *(const s16x8*)((char*)lV + d * 176 + kb3);
        o[0][nd] = __builtin_amdgcn_mfma_f32_16x16x32_bf16(pf0, vf, o[0][nd], 0, 0, 0);
        o[1][nd] = __builtin_amdgcn_mfma_f32_16x16x32_bf16(pf1, vf, o[1][nd], 0, 0, 0);
      }
    }
  }
#undef LOADT

#pragma unroll
  for (int m = 0; m < 2; ++m)
#pragma unroll
    for (int r = 0; r < 4; ++r) {
      float inv = 1.f / lrow[m][r];
      int row = q0 + (w << 5) + m * 16 + (lg << 2) + r;
      short* orow = Ob + hbase + (size_t)row * D_;
#pragma unroll
      for (int nd = 0; nd < 8; ++nd)
        orow[nd * 16 + li] = f2bf(o[m][nd][r] * inv);
    }
}

// ---------------- mask + residual + LayerNorm epilogue ----------------
__global__ __launch_bounds__(256) void ln_ep(const float* __restrict__ q,
                                             const short* __restrict__ Ob,
                                             const float* __restrict__ gam,
                                             const float* __restrict__ bet,
                                             float* __restrict__ out) {
  __shared__ float red[4][8];
  const int t = threadIdx.x;
  const int w = t >> 6, l = t & 63;
  const size_t off = (size_t)blockIdx.x * 1024 + t * 4;
  float4 qv = *(const float4*)(q + off);
  s16x4 ov = *(const s16x4*)(Ob + off);
  float oa[4] = {bf2f(ov[0]), bf2f(ov[1]), bf2f(ov[2]), bf2f(ov[3])};
  float qa[4] = {qv.x, qv.y, qv.z, qv.w};
  float s0 = 0, s1 = 0, s2 = 0, s3 = 0, s4 = 0, s5 = 0;
#pragma unroll
  for (int j = 0; j < 4; ++j) {
    s0 += fabsf(qa[j]);
    s1 += oa[j];
    s2 += qa[j];
    s3 += oa[j] * oa[j];
    s4 += oa[j] * qa[j];
    s5 += qa[j] * qa[j];
  }
#pragma unroll
  for (int d2 = 1; d2 < 64; d2 <<= 1) {
    s0 += __shfl_xor(s0, d2); s1 += __shfl_xor(s1, d2); s2 += __shfl_xor(s2, d2);
    s3 += __shfl_xor(s3, d2); s4 += __shfl_xor(s4, d2); s5 += __shfl_xor(s5, d2);
  }
  if (l == 0) {
    red[w][0] = s0; red[w][1] = s1; red[w][2] = s2;
    red[w][3] = s3; red[w][4] = s4; red[w][5] = s5;
  }
  __syncthreads();
  s0 = red[0][0] + red[1][0] + red[2][0] + red[3][0];
  s1 = red[0][1] + red[1][1] + red[2][1] + red[3][1];
  s2 = red[0][2] + red[1][2] + red[2][2] + red[3][2];
  s3 = red[0][3] + red[1][3] + red[2][3] + red[3][3];
  s4 = red[0][4] + red[1][4] + red[2][4] + red[3][4];
  s5 = red[0][5] + red[1][5] + red[2][5] + red[3][5];
  float msk = s0 > 0.f ? 1.f : 0.f;
  float sy = msk * s1 + s2;
  float sy2 = msk * s3 + 2.f * msk * s4 + s5;
  float mean = sy * (1.f / 1024.f);
  float var = sy2 * (1.f / 1024.f) - mean * mean;
  float inv = rsqrtf(fmaxf(var, 0.f) + 1e-8f);
  float4 gv = *(const float4*)(gam + t * 4);
  float4 bv = *(const float4*)(bet + t * 4);
  float4 rr;
  rr.x = (msk * oa[0] + qa[0] - mean) * inv * gv.x + bv.x;
  rr.y = (msk * oa[1] + qa[1] - mean) * inv * gv.y + bv.y;
  rr.z = (msk * oa[2] + qa[2] - mean) * inv * gv.z + bv.z;
  rr.w = (msk * oa[3] + qa[3] - mean) * inv * gv.w + bv.w;
  *(float4*)(out + off) = rr;
}

extern "C" void kernel_launch(void* const* d_in, const int* in_sizes, int n_in,
                              void* d_out, int out_size, void* d_ws, size_t ws_size,
                              hipStream_t stream) {
  const float* q   = (const float*)d_in[0];
  const float* k   = (const float*)d_in[1];
  const float* Wq  = (const float*)d_in[2];
  const float* bq  = (const float*)d_in[3];
  const float* Wk  = (const float*)d_in[4];
  const float* bk  = (const float*)d_in[5];
  const float* Wv  = (const float*)d_in[6];
  const float* bv  = (const float*)d_in[7];
  const float* gam = (const float*)d_in[8];
  const float* bet = (const float*)d_in[9];
  float* out = (float*)d_out;

  short* qb  = (short*)d_ws;        // 16M  queries bf16
  short* kb  = qb + 16777216;       // 16M  keys bf16
  short* wqb = kb + 16777216;       // 1M
  short* wkb = wqb + 1048576;       // 1M
  short* wvb = wkb + 1048576;       // 1M
  short* Qb  = wvb + 1048576;       // 16M (pre-scaled by QSCALE)
  short* Kb  = Qb + 16777216;       // 16M
  short* Vb  = Kb + 16777216;       // 16M
  short* Ob  = qb;                  // alias: qb dead after GEMM z=0 completes

  cvt_qk<<<16384, 256, 0, stream>>>(q, k, qb, kb);
  cvt_w<<<1536, 256, 0, stream>>>(Wq, Wk, Wv, wqb, wkb, wvb);
  gemm_qkv<<<dim3(256, 1, 3), 512, 0, stream>>>(qb, kb, wqb, wkb, wvb,
                                                bq, bk, bv, Qb, Kb, Vb);
  attn_kernel<<<1024, 256, 0, stream>>>(Qb, Kb, Vb, Ob);
  ln_ep<<<16384, 256, 0, stream>>>(q, Ob, gam, bet, out);
}